// Round 6
// baseline (442.437 us; speedup 1.0000x reference)
//
#include <hip/hip_runtime.h>
#include <math.h>
#include <stdint.h>

// image_batch (32,1,512,512) f32, angles (8,) f32 -> out (32,8,512,512) f32
#define N_IMG 32
#define N_ANG 8
#define H_ 512
#define W_ 512
#define HW (H_ * W_)

// R6: structural ablation of the LDS staging path. Each block's source
// footprint (~25 KB) is L1/L2-resident; gather taps directly from global
// with two dwordx2 row-pair loads per pixel. Removes: 25 global_load_lds
// per image, LDS write+read round trip, vmcnt drains, and (modeA) ALL
// barriers. LDS drops 51.2 KB -> 8.7 KB (modeB transpose only), occupancy
// 3 -> 5 blocks/CU. Boundary handling via setup-time weight-swap (exact).
#define TX 64
#define TY 32
// modeB transpose out-stage pitch: 32 rows x 68 words. 68%32=4 -> good
// bank spread for b128 accesses.
#define OP 68

typedef float f32x4 __attribute__((ext_vector_type(4)));
typedef float f32x2 __attribute__((ext_vector_type(2)));

__global__ __launch_bounds__(256, 5) void rotate_tile_kernel(
    const float* __restrict__ img,     // [N_IMG][H][W]
    const float* __restrict__ angles,  // [N_ANG] degrees
    float* __restrict__ out)           // [N_IMG][N_ANG][H][W]
{
    __shared__ float osb[TY * OP];     // modeB transpose buffer (8.7 KB)

    const int bz   = blockIdx.z;
    const int k    = bz >> 1;                  // angle
    const int n0   = (bz & 1) * (N_IMG / 2);   // image half
    const int tx0  = blockIdx.x * TX;
    const int ty0  = blockIdx.y * TY;
    const int tid  = threadIdx.x;

    const float rad = angles[k] * 0.017453292519943295f;
    float sa, ca;
    sincosf(rad, &sa, &ca);
    const float cx = (W_ - 1) * 0.5f;
    const float cy = (H_ - 1) * 0.5f;

    // ---- lane -> output-pixel mapping (block-uniform): lanes along x when
    // |cos|>=|sin| (consecutive lanes then stride ~1 along source rows ->
    // sector-coalesced tap loads), along y otherwise (near-90deg: source x
    // tracks output y). Also gives coalesced direct stores in modeA.
    const bool modeA = fabsf(ca) >= fabsf(sa);
    const int pxg = modeA ? (tid & 15) : (tid >> 4);
    const int py0 = modeA ? (tid >> 4) : (tid & 15);
    const int px  = pxg * 4;

    // ---- per-pixel setup (once, reused 16 images): two clamped row-pair
    // WORD offsets + 4 validity-premultiplied bilinear weights with exact
    // edge weight-swap:
    //   pair-load at xb=clamp(x0,0,510) returns L=(img[y][xb], img[y][xb+1]).
    //   x0 in [0,510]: taps are (L.x,L.y) with (w0,w1).
    //   x0 == -1   : valid tap x=0 is L.x  -> w0'=w1, w1'=0.
    //   x0 == 511  : valid tap x=511 is L.y-> w1'=w0, w0'=0.
    //   else       : both weights already 0.
    // Row clamps are independent (row0/row1 separate loads); y-validity is
    // premultiplied. All loads stay inside the image => always finite.
    int   o0[2][4], o1[2][4];
    float w00[2][4], w01[2][4], w10[2][4], w11[2][4];
#pragma unroll
    for (int p = 0; p < 2; ++p) {
        const int   yy = ty0 + py0 + p * 16;
        const float yr = (float)yy - cy;
#pragma unroll
        for (int j = 0; j < 4; ++j) {
            const int   xx = tx0 + px + j;
            const float xr = (float)xx - cx;
            const float sxs = ca * xr - sa * yr + cx;
            const float sys = sa * xr + ca * yr + cy;
            const float x0f = floorf(sxs), y0f = floorf(sys);
            const float wx = sxs - x0f, wy = sys - y0f;
            const int x0 = (int)x0f, y0 = (int)y0f;
            const bool vx0 = ((unsigned)x0       < (unsigned)W_);
            const bool vx1 = ((unsigned)(x0 + 1) < (unsigned)W_);
            const bool vy0 = ((unsigned)y0       < (unsigned)H_);
            const bool vy1 = ((unsigned)(y0 + 1) < (unsigned)H_);
            const int xb  = min(max(x0, 0), W_ - 2);
            const int yc0 = min(max(y0, 0), H_ - 1);
            const int yc1 = min(max(y0 + 1, 0), H_ - 1);
            o0[p][j] = yc0 * W_ + xb;
            o1[p][j] = yc1 * W_ + xb;
            const float omwx = 1.0f - wx, omwy = 1.0f - wy;
            float a = omwy * omwx * (float)(vy0 && vx0);   // tap(y0,x0)
            float b = omwy * wx   * (float)(vy0 && vx1);   // tap(y0,x1)
            float c = wy   * omwx * (float)(vy1 && vx0);   // tap(y1,x0)
            float d = wy   * wx   * (float)(vy1 && vx1);   // tap(y1,x1)
            if (x0 == -1)      { a = b; b = 0.0f; c = d; d = 0.0f; }
            else if (x0 == W_ - 1) { b = a; a = 0.0f; d = c; c = 0.0f; }
            w00[p][j] = a; w01[p][j] = b; w10[p][j] = c; w11[p][j] = d;
        }
    }

    // ---- per-image loop: 16 independent dwordx2 gathers (L1/L2 hits),
    // bilinear combine, coalesced nt store. No staging, no vmcnt waits;
    // modeA has zero barriers.
    for (int idx = 0; idx < N_IMG / 2; ++idx) {
        const int n = n0 + idx;
        const float* __restrict__ ibc = img + (size_t)n * HW;
        float* __restrict__ outn =
            out + ((size_t)(n * N_ANG + k) * H_ + ty0) * W_ + tx0;

        float v[2][4];
#pragma unroll
        for (int p = 0; p < 2; ++p) {
#pragma unroll
            for (int j = 0; j < 4; ++j) {
                const f32x2 L0 = *(const f32x2*)(ibc + o0[p][j]);
                const f32x2 L1 = *(const f32x2*)(ibc + o1[p][j]);
                v[p][j] = w00[p][j] * L0.x + w01[p][j] * L0.y
                        + w10[p][j] * L1.x + w11[p][j] * L1.y;
            }
        }

        if (modeA) {
            // lanes span x: 16 lanes x 16B = 256-B contiguous runs.
#pragma unroll
            for (int p = 0; p < 2; ++p) {
                f32x4 vv = { v[p][0], v[p][1], v[p][2], v[p][3] };
                __builtin_nontemporal_store(
                    vv, (f32x4*)(outn + (py0 + p * 16) * W_ + px));
            }
        } else {
            // modeB: lanes span y -> transpose through LDS, store coalesced.
#pragma unroll
            for (int p = 0; p < 2; ++p) {
                f32x4 vv = { v[p][0], v[p][1], v[p][2], v[p][3] };
                *(f32x4*)(osb + (py0 + p * 16) * OP + px) = vv;
            }
            asm volatile("s_waitcnt lgkmcnt(0)" ::: "memory");
            __builtin_amdgcn_sched_barrier(0);
            __builtin_amdgcn_s_barrier();
            const int rx = (tid & 15) * 4;   // coalesced (modeA-style) map
            const int ry = tid >> 4;
#pragma unroll
            for (int p = 0; p < 2; ++p) {
                f32x4 t = *(f32x4*)(osb + (ry + p * 16) * OP + rx);
                __builtin_nontemporal_store(
                    t, (f32x4*)(outn + (ry + p * 16) * W_ + rx));
            }
            // all waves' ds_reads are consumed (fed the stores above) before
            // they reach this barrier; next image's ds_writes are then safe.
            asm volatile("s_waitcnt lgkmcnt(0)" ::: "memory");
            __builtin_amdgcn_sched_barrier(0);
            __builtin_amdgcn_s_barrier();
        }
    }
}

extern "C" void kernel_launch(void* const* d_in, const int* in_sizes, int n_in,
                              void* d_out, int out_size, void* d_ws, size_t ws_size,
                              hipStream_t stream) {
    const float* img    = (const float*)d_in[0];
    const float* angles = (const float*)d_in[1];
    float* out          = (float*)d_out;

    dim3 block(256, 1, 1);
    dim3 grid(W_ / TX, H_ / TY, N_ANG * 2);  // 8 x 16 x 16 = 2048 blocks
    rotate_tile_kernel<<<grid, block, 0, stream>>>(img, angles, out);
}